// Round 12
// baseline (62.426 us; speedup 1.0000x reference)
//
#include <hip/hip_runtime.h>
#include <float.h>

// EuclideanCodebook R12: ring-3 single-barrier pipeline.
// Per chunk: [vmcnt(4): drains chunk ch (issued 2 iters ago, zero wait)]
// [s_barrier: ch resident block-wide + ring slot (ch+2)%3 free]
// [issue ch+2 DMA] [compute+score].  CH=32, 32 chunks, 1 barrier each.
// Core = R9's 16x16x32 f16-split (3 passes), A=codebook from LDS (wave-linear
// conflict-free), B=x in regs (32 rows/wave, 64 VGPR), 4 indep acc chains.
// score = 2*dot - e^2 (esq read from global/L1 in scoring; x^2 dropped).

#define Cdim        128
#define KCODES      1024
#define CH          32
#define NCH         32
#define BROWS       128       // 4 waves x 32 rows
#define THREADS     256
#define IMG_OFF     4096
#define CHUNK_BYTES 16384     // [hi: (ct*4+ks)*1KB x8 | lo: +8KB]

typedef _Float16 f16;
typedef __attribute__((ext_vector_type(8))) _Float16 f16x8;
typedef __attribute__((ext_vector_type(4))) float    f32x4;

#define MFMA16(A, B, C) __builtin_amdgcn_mfma_f32_16x16x32_f16((A), (B), (C), 0, 0, 0)

// ---------------- e_sq pre-pass (exact fp32) ----------------
__global__ __launch_bounds__(256) void esq_kernel(const float* __restrict__ embed,
                                                  float* __restrict__ esq, int K) {
    int gid  = blockIdx.x * blockDim.x + threadIdx.x;
    int code = gid >> 6;
    int lane = threadIdx.x & 63;
    if (code >= K) return;
    float2 v = ((const float2*)(embed + (size_t)code * Cdim))[lane];
    float  s = fmaf(v.x, v.x, v.y * v.y);
    #pragma unroll
    for (int m = 32; m >= 1; m >>= 1) s += __shfl_xor(s, m, 64);
    if (lane == 0) esq[code] = s;
}

__device__ __forceinline__ void cvt8s(float4 a, float4 b, float scale,
                                      f16x8& h, f16x8& lo) {
    float v[8] = {a.x, a.y, a.z, a.w, b.x, b.y, b.z, b.w};
    #pragma unroll
    for (int i = 0; i < 8; ++i) {
        float s = v[i] * scale;
        f16 hh = (f16)s;
        h[i]  = hh;
        lo[i] = (f16)(s - (float)hh);
    }
}

// ---- codebook -> 16x16x32-fragment image, wave-linear lane order ----
// A-frag: lane l holds e[code = base + (l&15)][k = ks*32 + (l>>4)*8 ..+8]
// hi: IMG_OFF + ch*16384 + (ct*4+ks)*1024 + ((l>>4)*16 + (l&15))*16; lo +8192
__global__ __launch_bounds__(256) void bconv_kernel(const float* __restrict__ embed,
                                                    char* __restrict__ ws) {
    int t    = blockIdx.x * 256 + threadIdx.x;   // 16384 threads
    int code = t >> 4;
    int seg  = t & 15;
    int ks   = seg >> 2;
    int kseg = seg & 3;
    int ch = code >> 5, ct = (code >> 4) & 1, lr = code & 15;
    const float4* p = (const float4*)(embed + (size_t)code * Cdim + ks * 32 + kseg * 8);
    f16x8 h, lo;
    cvt8s(p[0], p[1], 1.0f, h, lo);
    size_t base = (size_t)IMG_OFF + (size_t)ch * CHUNK_BYTES
                + (ct * 4 + ks) * 1024 + (kseg * 16 + lr) * 16;
    *(f16x8*)(ws + base)        = h;
    *(f16x8*)(ws + base + 8192) = lo;
}

// ---------------- async global->LDS 16B ----------------
__device__ __forceinline__ void gll16(const void* g, void* l) {
    __builtin_amdgcn_global_load_lds(
        (const __attribute__((address_space(1))) unsigned int*)g,
        (__attribute__((address_space(3))) unsigned int*)l, 16, 0, 0);
}

__global__ __launch_bounds__(THREADS, 2) void vq_kernel(
    const float* __restrict__ x, const float* __restrict__ embed,
    const char* __restrict__ ws, float* __restrict__ outq,
    float* __restrict__ outi) {

    __shared__ __align__(16) char Bb[3][CHUNK_BYTES];   // 48KB ring

    const int tid  = threadIdx.x;
    const int wid  = tid >> 6;          // wave 0..3, owns rows wid*32..+31
    const int l    = tid & 63;
    const int lr   = l & 15;            // x-row within 16-tile
    const int lg   = l >> 4;            // k-seg (inputs) / code-subrow (outputs)
    const int row0 = blockIdx.x * BROWS;
    const int wrow = row0 + wid * 32;

    // ---- prologue DMA: chunks 0 and 1 (4KB/wave each) ----
    #pragma unroll
    for (int b = 0; b < 2; ++b) {
        const char* src = ws + IMG_OFF + b * CHUNK_BYTES + wid * 4096 + (size_t)l * 16;
        char*       dst = &Bb[b][wid * 4096];
        #pragma unroll
        for (int i = 0; i < 4; ++i) gll16(src + i * 1024, dst + i * 1024);
    }

    // ---- x rows -> B-fragments (2*xh, 2*xl): rows wrow + rt*16 + lr ----
    f16x8 bxh[2][4], bxl[2][4];
    #pragma unroll
    for (int rt = 0; rt < 2; ++rt) {
        const float* xr = x + (size_t)(wrow + rt * 16 + lr) * Cdim + lg * 8;
        #pragma unroll
        for (int ks = 0; ks < 4; ++ks) {
            float4 v0 = *(const float4*)(xr + ks * 32);
            float4 v1 = *(const float4*)(xr + ks * 32 + 4);
            cvt8s(v0, v1, 2.0f, bxh[rt][ks], bxl[rt][ks]);
        }
    }

    const float* esqp = (const float*)ws;

    float best[2] = {-FLT_MAX, -FLT_MAX};
    int   bidx[2] = {0, 0};
    int cur = 0, pf = 2;

    #pragma unroll 1
    for (int ch = 0; ch < NCH; ++ch) {
        // chunk ch's DMA was issued 2 iterations ago -> this never waits.
        if (ch == NCH - 1) asm volatile("s_waitcnt vmcnt(0)" ::: "memory");
        else               asm volatile("s_waitcnt vmcnt(4)" ::: "memory");
        // all waves' ch loads drained AND everyone done reading slot (ch-1)%3
        __builtin_amdgcn_s_barrier();

        if (ch + 2 < NCH) {   // issue chunk ch+2 into the freed ring slot
            const char* src = ws + IMG_OFF + (size_t)(ch + 2) * CHUNK_BYTES
                            + wid * 4096 + (size_t)l * 16;
            char* dst = &Bb[0][0] + (size_t)pf * CHUNK_BYTES + wid * 4096;
            #pragma unroll
            for (int i = 0; i < 4; ++i) gll16(src + i * 1024, dst + i * 1024);
        }

        f32x4 acc[2][2];
        #pragma unroll
        for (int ct = 0; ct < 2; ++ct)
            #pragma unroll
            for (int rt = 0; rt < 2; ++rt)
                acc[ct][rt] = (f32x4){0.f, 0.f, 0.f, 0.f};

        const char* bb = &Bb[0][0] + (size_t)cur * CHUNK_BYTES + (size_t)l * 16;

        #pragma unroll
        for (int ks = 0; ks < 4; ++ks) {
            f16x8 eh0 = *(const f16x8*)(bb + ks * 1024);
            f16x8 el0 = *(const f16x8*)(bb + ks * 1024 + 8192);
            f16x8 eh1 = *(const f16x8*)(bb + (4 + ks) * 1024);
            f16x8 el1 = *(const f16x8*)(bb + (4 + ks) * 1024 + 8192);

            __builtin_amdgcn_s_setprio(1);
            // pass 1: eh * 2xh  (4 chains, reuse distance 4)
            acc[0][0] = MFMA16(eh0, bxh[0][ks], acc[0][0]);
            acc[0][1] = MFMA16(eh0, bxh[1][ks], acc[0][1]);
            acc[1][0] = MFMA16(eh1, bxh[0][ks], acc[1][0]);
            acc[1][1] = MFMA16(eh1, bxh[1][ks], acc[1][1]);
            // pass 2: eh * 2xl
            acc[0][0] = MFMA16(eh0, bxl[0][ks], acc[0][0]);
            acc[0][1] = MFMA16(eh0, bxl[1][ks], acc[0][1]);
            acc[1][0] = MFMA16(eh1, bxl[0][ks], acc[1][0]);
            acc[1][1] = MFMA16(eh1, bxl[1][ks], acc[1][1]);
            // pass 3: el * 2xh
            acc[0][0] = MFMA16(el0, bxh[0][ks], acc[0][0]);
            acc[0][1] = MFMA16(el0, bxh[1][ks], acc[0][1]);
            acc[1][0] = MFMA16(el1, bxh[0][ks], acc[1][0]);
            acc[1][1] = MFMA16(el1, bxh[1][ks], acc[1][1]);
            __builtin_amdgcn_s_setprio(0);
        }

        // scoring: s = 2*dot - e^2; codes ascend (ct, then j), strict >
        #pragma unroll
        for (int ct = 0; ct < 2; ++ct) {
            const int cb = ch * CH + ct * 16 + lg * 4;
            float4 e4 = *(const float4*)(esqp + cb);
            #pragma unroll
            for (int rt = 0; rt < 2; ++rt)
                #pragma unroll
                for (int j = 0; j < 4; ++j) {
                    float s = acc[ct][rt][j] - ((const float*)&e4)[j];
                    if (s > best[rt]) { best[rt] = s; bidx[rt] = cb + j; }
                }
        }

        cur = (cur == 2) ? 0 : cur + 1;
        pf  = (pf  == 2) ? 0 : pf  + 1;
    }

    // ---- reduce over lg (lanes lr, lr+16, lr+32, lr+48 share each row) ----
    __syncthreads();                      // ring no longer read; reuse as winners
    int* winners = (int*)&Bb[0][0];
    #pragma unroll
    for (int rt = 0; rt < 2; ++rt) {
        float bs = best[rt]; int bi = bidx[rt];
        #pragma unroll
        for (int m = 16; m <= 32; m <<= 1) {
            float vs = __shfl_xor(bs, m, 64);
            int   vi = __shfl_xor(bi, m, 64);
            if (vs > bs || (vs == bs && vi < bi)) { bs = vs; bi = vi; }
        }
        if (lg == 0) {
            winners[wid * 32 + rt * 16 + lr] = bi;
            outi[wrow + rt * 16 + lr] = (float)bi;
        }
    }
    __syncthreads();

    // ---- gather quantized = embed[winner] (exact fp32 copy) ----
    #pragma unroll
    for (int i = 0; i < 16; ++i) {
        int pos = i * THREADS + tid;
        int r = pos >> 5, c4 = pos & 31;
        int idx = winners[r];
        float4 v = ((const float4*)(embed + (size_t)idx * Cdim))[c4];
        ((float4*)(outq + (size_t)(row0 + r) * Cdim))[c4] = v;
    }
}

extern "C" void kernel_launch(void* const* d_in, const int* in_sizes, int n_in,
                              void* d_out, int out_size, void* d_ws, size_t ws_size,
                              hipStream_t stream) {
    const float* x     = (const float*)d_in[0];
    const float* embed = (const float*)d_in[1];
    const int M = in_sizes[0] / Cdim;   // 65536
    const int K = in_sizes[1] / Cdim;   // 1024
    float* outq = (float*)d_out;
    float* outi = outq + (size_t)M * Cdim;

    esq_kernel <<<K / 4, 256, 0, stream>>>(embed, (float*)d_ws, K);
    bconv_kernel<<<64, 256, 0, stream>>>(embed, (char*)d_ws);
    vq_kernel  <<<M / BROWS, THREADS, 0, stream>>>(x, embed, (const char*)d_ws,
                                                   outq, outi);
}